// Round 8
// baseline (231.452 us; speedup 1.0000x reference)
//
#include <hip/hip_runtime.h>

// ---------------------------------------------------------------------------
// DigitConvolutionalModel: x(32768,784) -> conv3x3(valid) -> 676
//   -> relu(@W1(676,300)+b1) -> relu(@W2(300,300)+b2) -> @W3(300,10)+b3
//
// R8: two-phase design.
//  1) xconvert: pure streaming fp32->bf16, PERFECTLY coalesced reads (fill-
//     shaped), writes x into MFMA A-fragment layout xf[t][kc][64 lanes][8].
//  2) fused_mlp: GEMM1 K-loop has ZERO barriers and ZERO LDS: A-frags are
//     single dwordx4 loads from xf (L3-hot), B-frags global->regs, both
//     double-buffered one chunk ahead. Only 4 barriers total (h exchanges).
//  conv folded into W1eff (K 784->800 zero-pad, N 300->320 pad) as before.
// ---------------------------------------------------------------------------

typedef __bf16 bf16_t;
typedef __bf16 bf16x4 __attribute__((ext_vector_type(4)));
typedef __bf16 bf16x8 __attribute__((ext_vector_type(8)));
typedef float  f32x4  __attribute__((ext_vector_type(4)));

#define MFMA16(a, b, c) __builtin_amdgcn_mfma_f32_16x16x32_bf16((a), (b), (c), 0, 0, 0)

#define W1F_ELEMS (25 * 20 * 64 * 8)  // 256000  (K=800, N=320)
#define W2F_ELEMS (10 * 20 * 64 * 8)  // 102400  (K=320, N=320)
#define W3F_ELEMS (10 * 1 * 64 * 8)   // 5120    (K=320, N=16)
#define XF_OFF    768000              // byte offset of xf in ws
#define XF_BYTES  ((size_t)2048 * 25 * 64 * 16)  // 51.2 MB

// ---------------------------------------------------------------------------
__global__ void prep_weights(const float* __restrict__ conv_w,
                             const float* __restrict__ W1,
                             const float* __restrict__ W2,
                             const float* __restrict__ W3,
                             bf16_t* __restrict__ W1f,
                             bf16_t* __restrict__ W2f,
                             bf16_t* __restrict__ W3f) {
    int idx = blockIdx.x * 256 + threadIdx.x;
    if (idx < 800 * 320) {
        int k = idx / 320;
        int n = idx - k * 320;
        float v = 0.0f;
        if (k < 784 && n < 300) {
            int py = k / 28;
            int px = k - py * 28;
#pragma unroll
            for (int ky = 0; ky < 3; ++ky) {
                int oy = py - ky;
                if (oy < 0 || oy > 25) continue;
#pragma unroll
                for (int kx = 0; kx < 3; ++kx) {
                    int ox = px - kx;
                    if (ox < 0 || ox > 25) continue;
                    v += conv_w[ky * 3 + kx] * W1[(oy * 26 + ox) * 300 + n];
                }
            }
        }
        int kc = k >> 5, quad = (k >> 3) & 3, j = k & 7;
        int nt = n >> 4, nin = n & 15;
        W1f[(((kc * 20 + nt) * 64 + quad * 16 + nin) << 3) + j] = (bf16_t)v;
    } else if (idx < 800 * 320 + 320 * 320) {
        int i2 = idx - 800 * 320;
        int k = i2 / 320;
        int n = i2 - k * 320;
        float v = (k < 300 && n < 300) ? W2[k * 300 + n] : 0.0f;
        int kc = k >> 5, quad = (k >> 3) & 3, j = k & 7;
        int nt = n >> 4, nin = n & 15;
        W2f[(((kc * 20 + nt) * 64 + quad * 16 + nin) << 3) + j] = (bf16_t)v;
    } else if (idx < 800 * 320 + 320 * 320 + 320 * 16) {
        int i3 = idx - (800 * 320 + 320 * 320);
        int k = i3 / 16;
        int n = i3 - k * 16;
        float v = (k < 300 && n < 10) ? W3[k * 10 + n] : 0.0f;
        int kc = k >> 5, quad = (k >> 3) & 3, j = k & 7;
        W3f[(((kc * 64) + quad * 16 + n) << 3) + j] = (bf16_t)v;
    }
}

// ---------------------------------------------------------------------------
// xconvert: fp32 x -> bf16 in A-frag layout.
// xf 16B-slot index for (t=row/16, kc, q, l15=row&15): (t*25+kc)*64 + q*16 + l15
// Main range: one thread per float4 of x (PERFECTLY contiguous reads).
// Tail range: zero k=784..799 (q=2,3 of kc=24).
// ---------------------------------------------------------------------------
#define XMAIN (32768 * 196)   // 6422528 float4s
#define XZERO (2048 * 32 * 2) // 131072 8B-zero writes

__global__ void xconvert(const float* __restrict__ x, bf16_t* __restrict__ xf) {
    int idx = blockIdx.x * 256 + threadIdx.x;
    if (idx < XMAIN) {
        float4 v = ((const float4*)x)[idx];
        int row = idx / 196;
        int c4  = idx - row * 196;
        int t = row >> 4, l15 = row & 15;
        int kc = c4 >> 3, q = (c4 >> 1) & 3, half = c4 & 1;
        bf16x4 o;
        o[0] = (bf16_t)v.x; o[1] = (bf16_t)v.y;
        o[2] = (bf16_t)v.z; o[3] = (bf16_t)v.w;
        size_t slot = ((size_t)t * 25 + kc) * 64 + q * 16 + l15;
        *(bf16x4*)(xf + slot * 8 + half * 4) = o;
    } else {
        int z = idx - XMAIN;
        if (z < XZERO) {
            int half = z & 1;
            int z2 = z >> 1;          // (t, qq, l15)
            int t = z2 >> 5;
            int r5 = z2 & 31;
            int qq = r5 >> 4, l15 = r5 & 15;
            size_t slot = ((size_t)t * 25 + 24) * 64 + (2 + qq) * 16 + l15;
            bf16x4 o = (bf16x4){(bf16_t)0.f, (bf16_t)0.f, (bf16_t)0.f, (bf16_t)0.f};
            *(bf16x4*)(xf + slot * 8 + half * 4) = o;
        }
    }
}

// ---------------------------------------------------------------------------
// fused_mlp: out = relu(relu(x@W1eff+b1)@W2+b2)@W3+b3.
// 512 blocks x 64 rows, 512 thr = 8 waves; wave (mh=w&1, nq=w>>1):
// rows mh*32..+31 (2 m-tiles), n-tiles nq*5..+4.
// GEMM1/GEMM2 K-loops: no barriers. A-frags: dwordx4 from xf / LDS h1.
// B-frags: global->regs, 1-chunk lookahead. 4 barriers total.
// ---------------------------------------------------------------------------
__global__ __launch_bounds__(512, 2) void fused_mlp(
    const bf16x8* __restrict__ xf, const float* __restrict__ b1,
    const float* __restrict__ b2, const float* __restrict__ b3,
    const bf16x8* __restrict__ W1f, const bf16x8* __restrict__ W2f,
    const bf16x8* __restrict__ W3f, float* __restrict__ out) {
    __shared__ bf16x8 hbuf[10 * 4 * 64];  // 40 KB: h in A-frag order

    const int tid = threadIdx.x;
    const int w   = tid >> 6;
    const int l   = tid & 63;
    const int mh  = w & 1;
    const int nq  = w >> 1;
    const int q   = l >> 4;
    const int l15 = l & 15;
    const int r0  = blockIdx.x * 64;

    // A-frag base: tile t = blockIdx*4 + mh*2 + mt2, frag (t*25+kc)*64 + l
    const bf16x8* xa0 = xf + ((size_t)(blockIdx.x * 4 + mh * 2 + 0) * 25) * 64 + l;
    const bf16x8* xa1 = xf + ((size_t)(blockIdx.x * 4 + mh * 2 + 1) * 25) * 64 + l;
    const bf16x8* wb1 = W1f + (nq * 5) * 64 + l;

    f32x4 acc[2][5];
#pragma unroll
    for (int m = 0; m < 2; ++m)
#pragma unroll
        for (int nt = 0; nt < 5; ++nt) acc[m][nt] = (f32x4){0.f, 0.f, 0.f, 0.f};

    // ---------------- GEMM1: 25 chunks, zero barriers ----------------------
    bf16x8 a0[2], a1[2], bfr[2][5];
    a0[0] = xa0[0];
    a1[0] = xa1[0];
#pragma unroll
    for (int nt = 0; nt < 5; ++nt) bfr[0][nt] = wb1[nt * 64];

    for (int kc = 0; kc < 25; ++kc) {
        const int cur = kc & 1, nxt = cur ^ 1;
        if (kc + 1 < 25) {
            a0[nxt] = xa0[(kc + 1) * 64];
            a1[nxt] = xa1[(kc + 1) * 64];
            const bf16x8* wb = wb1 + (size_t)(kc + 1) * 20 * 64;
#pragma unroll
            for (int nt = 0; nt < 5; ++nt) bfr[nxt][nt] = wb[nt * 64];
        }
#pragma unroll
        for (int nt = 0; nt < 5; ++nt) {
            acc[0][nt] = MFMA16(a0[cur], bfr[cur][nt], acc[0][nt]);
            acc[1][nt] = MFMA16(a1[cur], bfr[cur][nt], acc[1][nt]);
        }
    }

    // ---------------- h1 = relu(C1+b1) -> hbuf (A-frag order) --------------
    {
        bf16_t* hb = (bf16_t*)hbuf;
#pragma unroll
        for (int nt = 0; nt < 5; ++nt) {
            int n = (nq * 5 + nt) * 16 + l15;
            float bias = (n < 300) ? b1[n] : 0.0f;
            int kc2 = n >> 5, quad = (n >> 3) & 3, j = n & 7;
#pragma unroll
            for (int mt2 = 0; mt2 < 2; ++mt2) {
                int mt = mh * 2 + mt2;
#pragma unroll
                for (int r = 0; r < 4; ++r) {
                    float v = acc[mt2][nt][r] + bias;
                    v = v > 0.f ? v : 0.f;
                    hb[(((kc2 * 4 + mt) * 64 + quad * 16 + q * 4 + r) << 3) + j] =
                        (bf16_t)v;
                }
            }
        }
    }
    __syncthreads();

    // ---------------- GEMM2: 10 chunks, zero barriers ----------------------
#pragma unroll
    for (int m = 0; m < 2; ++m)
#pragma unroll
        for (int nt = 0; nt < 5; ++nt) acc[m][nt] = (f32x4){0.f, 0.f, 0.f, 0.f};
    const bf16x8* wb2 = W2f + (nq * 5) * 64 + l;
    bf16x8 b2f[2][5];
#pragma unroll
    for (int nt = 0; nt < 5; ++nt) b2f[0][nt] = wb2[nt * 64];

    for (int kc = 0; kc < 10; ++kc) {
        const int cur = kc & 1, nxt = cur ^ 1;
        if (kc + 1 < 10) {
            const bf16x8* wb = wb2 + (size_t)(kc + 1) * 20 * 64;
#pragma unroll
            for (int nt = 0; nt < 5; ++nt) b2f[nxt][nt] = wb[nt * 64];
        }
        bf16x8 ha0 = hbuf[(kc * 4 + mh * 2 + 0) * 64 + l];
        bf16x8 ha1 = hbuf[(kc * 4 + mh * 2 + 1) * 64 + l];
#pragma unroll
        for (int nt = 0; nt < 5; ++nt) {
            acc[0][nt] = MFMA16(ha0, b2f[cur][nt], acc[0][nt]);
            acc[1][nt] = MFMA16(ha1, b2f[cur][nt], acc[1][nt]);
        }
    }
    __syncthreads();  // done reading h1 before overwrite

    // ---------------- h2 = relu(C2+b2) -> hbuf -----------------------------
    {
        bf16_t* hb = (bf16_t*)hbuf;
#pragma unroll
        for (int nt = 0; nt < 5; ++nt) {
            int n = (nq * 5 + nt) * 16 + l15;
            float bias = (n < 300) ? b2[n] : 0.0f;
            int kc2 = n >> 5, quad = (n >> 3) & 3, j = n & 7;
#pragma unroll
            for (int mt2 = 0; mt2 < 2; ++mt2) {
                int mt = mh * 2 + mt2;
#pragma unroll
                for (int r = 0; r < 4; ++r) {
                    float v = acc[mt2][nt][r] + bias;
                    v = v > 0.f ? v : 0.f;
                    hb[(((kc2 * 4 + mt) * 64 + quad * 16 + q * 4 + r) << 3) + j] =
                        (bf16_t)v;
                }
            }
        }
    }
    __syncthreads();

    // ---------------- GEMM3: waves 0-3 (mt=w); W3 frags from global --------
    if (w < 4) {
        f32x4 acc3 = (f32x4){0.f, 0.f, 0.f, 0.f};
#pragma unroll
        for (int kc = 0; kc < 10; ++kc)
            acc3 = MFMA16(hbuf[(kc * 4 + w) * 64 + l], W3f[kc * 64 + l], acc3);
        if (l15 < 10) {
            float bias = b3[l15];
#pragma unroll
            for (int r = 0; r < 4; ++r)
                out[(size_t)(r0 + w * 16 + q * 4 + r) * 10 + l15] = acc3[r] + bias;
        }
    }
}

// ---------------------------------------------------------------------------
extern "C" void kernel_launch(void* const* d_in, const int* in_sizes, int n_in,
                              void* d_out, int out_size, void* d_ws, size_t ws_size,
                              hipStream_t stream) {
    const float* x      = (const float*)d_in[0];
    const float* conv_w = (const float*)d_in[1];
    const float* W1     = (const float*)d_in[2];
    const float* b1     = (const float*)d_in[3];
    const float* W2     = (const float*)d_in[4];
    const float* b2     = (const float*)d_in[5];
    const float* W3     = (const float*)d_in[6];
    const float* b3     = (const float*)d_in[7];
    float* out = (float*)d_out;

    char* ws = (char*)d_ws;
    bf16_t* W1f = (bf16_t*)(ws);
    bf16_t* W2f = (bf16_t*)(ws + (size_t)W1F_ELEMS * 2);
    bf16_t* W3f = (bf16_t*)(ws + (size_t)(W1F_ELEMS + W2F_ELEMS) * 2);
    bf16_t* xf  = (bf16_t*)(ws + XF_OFF);
    if (ws_size < XF_OFF + XF_BYTES) return;  // need ~52 MB scratch

    int prep_total = 800 * 320 + 320 * 320 + 320 * 16;  // 363520
    prep_weights<<<(prep_total + 255) / 256, 256, 0, stream>>>(
        conv_w, W1, W2, W3, W1f, W2f, W3f);

    xconvert<<<(XMAIN + XZERO) / 256, 256, 0, stream>>>(x, xf);

    fused_mlp<<<32768 / 64, 512, 0, stream>>>(
        (const bf16x8*)xf, b1, b2, b3, (const bf16x8*)W1f,
        (const bf16x8*)W2f, (const bf16x8*)W3f, out);
}